// Round 5
// baseline (252.116 us; speedup 1.0000x reference)
//
#include <hip/hip_runtime.h>

#define ITERS 20
#define EPS 1e-9f

typedef _Float16 half2_t __attribute__((ext_vector_type(2)));

// f32x2 -> packed f16x2 (v_cvt_pkrtz_f16_f32), bit-cast to fdot2's operand type
__device__ __forceinline__ half2_t pkrtz(float a, float b) {
    return __builtin_bit_cast(half2_t, __builtin_amdgcn_cvt_pkrtz(a, b));
}

// butterfly add with partner lane^stride via DPP (VALU pipe)
template <int CTRL>
__device__ __forceinline__ float dpp_add(float x) {
    int yi = __builtin_amdgcn_update_dpp(0, __float_as_int(x), CTRL, 0xf, 0xf, true);
    return x + __int_as_float(yi);
}

// xor16 butterfly sum: v_permlane16_swap_b32 exchanges 16-lane chunks between
// two registers; with both inputs = x, sum of the two results = x[l] + x[l^16]
// in every lane. Builtin returns an SSA pair -> allocator cannot coalesce the
// operands (the round-4 inline-asm bug).
__device__ __forceinline__ float swap16_add(float x) {
#if __has_builtin(__builtin_amdgcn_permlane16_swap)
    auto r = __builtin_amdgcn_permlane16_swap(__float_as_uint(x), __float_as_uint(x),
                                              false, false);
    return __uint_as_float(r[0]) + __uint_as_float(r[1]);
#else
    return x + __shfl_xor(x, 16, 64);
#endif
}
// xor32 butterfly sum via v_permlane32_swap_b32
__device__ __forceinline__ float swap32_add(float x) {
#if __has_builtin(__builtin_amdgcn_permlane32_swap)
    auto r = __builtin_amdgcn_permlane32_swap(__float_as_uint(x), __float_as_uint(x),
                                              false, false);
    return __uint_as_float(r[0]) + __uint_as_float(r[1]);
#else
    return x + __shfl_xor(x, 32, 64);
#endif
}

__device__ __forceinline__ float fdot2(half2_t a, half2_t b, float c) {
#if __has_builtin(__builtin_amdgcn_fdot2)
    return __builtin_amdgcn_fdot2(a, b, c, false);
#else
    return fmaf((float)a.x, (float)b.x, fmaf((float)a.y, (float)b.y, c));
#endif
}

// One wave per 64x64 matrix; lane (bi,bj) owns an 8x8 sub-block held as f16:
//   bc[r][c2] = (E[r][2c2], E[r][2c2+1])   — packed along columns (row matvec)
//   br[c][r2] = (E[2r2][c], E[2r2+1][c])   — packed along row pairs (col matvec)
// Sinkhorn iterate M = E .* (u v^T); only u,v (f32) update each iteration.
__global__ __launch_bounds__(256, 4) void sinkhorn_kernel(
        const float* __restrict__ x, float* __restrict__ out, int nmat) {
    const int lane = threadIdx.x & 63;
    const int wave = threadIdx.x >> 6;
    const int mat  = blockIdx.x * 4 + wave;
    if (mat >= nmat) return;
    const int bi = lane >> 3;   // block-row 0..7
    const int bj = lane & 7;    // block-col 0..7

    const float4* __restrict__ xin = (const float4*)(x + (size_t)mat * 4096);

    half2_t bc[8][4];   // row-major, col-packed
    half2_t br[8][4];   // col-major, row-pair-packed
    #pragma unroll
    for (int r2 = 0; r2 < 4; ++r2) {
        float4 a0 = xin[(8 * bi + 2 * r2 + 0) * 16 + 2 * bj + 0];
        float4 a1 = xin[(8 * bi + 2 * r2 + 0) * 16 + 2 * bj + 1];
        float4 c0 = xin[(8 * bi + 2 * r2 + 1) * 16 + 2 * bj + 0];
        float4 c1 = xin[(8 * bi + 2 * r2 + 1) * 16 + 2 * bj + 1];
        float e0[8] = {__expf(a0.x), __expf(a0.y), __expf(a0.z), __expf(a0.w),
                       __expf(a1.x), __expf(a1.y), __expf(a1.z), __expf(a1.w)};
        float e1[8] = {__expf(c0.x), __expf(c0.y), __expf(c0.z), __expf(c0.w),
                       __expf(c1.x), __expf(c1.y), __expf(c1.z), __expf(c1.w)};
        #pragma unroll
        for (int c2 = 0; c2 < 4; ++c2) {
            bc[2 * r2 + 0][c2] = pkrtz(e0[2 * c2], e0[2 * c2 + 1]);
            bc[2 * r2 + 1][c2] = pkrtz(e1[2 * c2], e1[2 * c2 + 1]);
        }
        #pragma unroll
        for (int c = 0; c < 8; ++c)
            br[c][r2] = pkrtz(e0[c], e1[c]);
    }

    float uu[8], vv[8];
    #pragma unroll
    for (int i = 0; i < 8; ++i) { uu[i] = 1.0f; vv[i] = 1.0f; }

    for (int it = 0; it < ITERS; ++it) {
        // ---- row normalization: rowsum_i = u_i * sum_j E[i,j] v_j ----
        half2_t vvh[4];
        #pragma unroll
        for (int c2 = 0; c2 < 4; ++c2)
            vvh[c2] = pkrtz(vv[2 * c2], vv[2 * c2 + 1]);
        float p[8];
        #pragma unroll
        for (int r = 0; r < 8; ++r) {
            float s = 0.0f;
            #pragma unroll
            for (int c2 = 0; c2 < 4; ++c2) s = fdot2(bc[r][c2], vvh[c2], s);
            p[r] = s;
        }
        // all-reduce over the 8 lanes sharing bi (lane bits 0-2): pure DPP
        #pragma unroll
        for (int r = 0; r < 8; ++r) p[r] = dpp_add<0xB1>(p[r]);   // xor1
        #pragma unroll
        for (int r = 0; r < 8; ++r) p[r] = dpp_add<0x4E>(p[r]);   // xor2
        #pragma unroll
        for (int r = 0; r < 8; ++r) p[r] = dpp_add<0x141>(p[r]);  // half-mirror completes 8-lane sum
        #pragma unroll
        for (int r = 0; r < 8; ++r) {
            float S = fmaf(uu[r], p[r], EPS);
            uu[r] *= __builtin_amdgcn_rcpf(S);
        }

        // ---- col normalization: colsum_j = v_j * sum_i E[i,j] u_i ----
        half2_t uuh[4];
        #pragma unroll
        for (int r2 = 0; r2 < 4; ++r2)
            uuh[r2] = pkrtz(uu[2 * r2], uu[2 * r2 + 1]);
        float q[8];
        #pragma unroll
        for (int c = 0; c < 8; ++c) {
            float s = 0.0f;
            #pragma unroll
            for (int r2 = 0; r2 < 4; ++r2) s = fdot2(br[c][r2], uuh[r2], s);
            q[c] = s;
        }
        // all-reduce over the 8 lanes sharing bj (lane bits 3-5): VALU only
        #pragma unroll
        for (int c = 0; c < 8; ++c) q[c] = dpp_add<0x128>(q[c]);  // row_ror:8 = xor8
        #pragma unroll
        for (int c = 0; c < 8; ++c) q[c] = swap16_add(q[c]);      // xor16
        #pragma unroll
        for (int c = 0; c < 8; ++c) q[c] = swap32_add(q[c]);      // xor32
        #pragma unroll
        for (int c = 0; c < 8; ++c) {
            float T = fmaf(vv[c], q[c], EPS);
            vv[c] *= __builtin_amdgcn_rcpf(T);
        }
    }

    // ---- epilogue: out = E .* (u v^T) ----
    float4* __restrict__ o = (float4*)(out + (size_t)mat * 4096);
    #pragma unroll
    for (int r = 0; r < 8; ++r) {
        float ur = uu[r];
        float4 lo, hi;
        lo.x = (float)bc[r][0].x * ur * vv[0];
        lo.y = (float)bc[r][0].y * ur * vv[1];
        lo.z = (float)bc[r][1].x * ur * vv[2];
        lo.w = (float)bc[r][1].y * ur * vv[3];
        hi.x = (float)bc[r][2].x * ur * vv[4];
        hi.y = (float)bc[r][2].y * ur * vv[5];
        hi.z = (float)bc[r][3].x * ur * vv[6];
        hi.w = (float)bc[r][3].y * ur * vv[7];
        o[(8 * bi + r) * 16 + 2 * bj + 0] = lo;
        o[(8 * bi + r) * 16 + 2 * bj + 1] = hi;
    }
}

extern "C" void kernel_launch(void* const* d_in, const int* in_sizes, int n_in,
                              void* d_out, int out_size, void* d_ws, size_t ws_size,
                              hipStream_t stream) {
    const float* x = (const float*)d_in[0];
    float* out = (float*)d_out;
    const int nmat = in_sizes[0] / 4096;          // 8192 matrices of 64x64
    const int blocks = (nmat + 3) / 4;            // 4 matrices (waves) per block
    sinkhorn_kernel<<<blocks, 256, 0, stream>>>(x, out, nmat);
}

// Round 6
// 251.765 us; speedup vs baseline: 1.0014x; 1.0014x over previous
//
#include <hip/hip_runtime.h>

#define ITERS 20

typedef _Float16 half2_t __attribute__((ext_vector_type(2)));

// f32x2 -> packed f16x2 (v_cvt_pkrtz_f16_f32)
__device__ __forceinline__ half2_t pkrtz(float a, float b) {
    return __builtin_bit_cast(half2_t, __builtin_amdgcn_cvt_pkrtz(a, b));
}

// butterfly add with partner lane^stride via DPP (VALU pipe)
template <int CTRL>
__device__ __forceinline__ float dpp_add(float x) {
    int yi = __builtin_amdgcn_update_dpp(0, __float_as_int(x), CTRL, 0xf, 0xf, true);
    return x + __int_as_float(yi);
}

// xor16 / xor32 butterfly sums via gfx950 permlane*_swap (verified round 5)
__device__ __forceinline__ float swap16_add(float x) {
#if __has_builtin(__builtin_amdgcn_permlane16_swap)
    auto r = __builtin_amdgcn_permlane16_swap(__float_as_uint(x), __float_as_uint(x),
                                              false, false);
    return __uint_as_float(r[0]) + __uint_as_float(r[1]);
#else
    return x + __shfl_xor(x, 16, 64);
#endif
}
__device__ __forceinline__ float swap32_add(float x) {
#if __has_builtin(__builtin_amdgcn_permlane32_swap)
    auto r = __builtin_amdgcn_permlane32_swap(__float_as_uint(x), __float_as_uint(x),
                                              false, false);
    return __uint_as_float(r[0]) + __uint_as_float(r[1]);
#else
    return x + __shfl_xor(x, 32, 64);
#endif
}

__device__ __forceinline__ float fdot2(half2_t a, half2_t b, float c) {
#if __has_builtin(__builtin_amdgcn_fdot2)
    return __builtin_amdgcn_fdot2(a, b, c, false);
#else
    return fmaf((float)a.x, (float)b.x, fmaf((float)a.y, (float)b.y, c));
#endif
}

__device__ __forceinline__ float frcp(float x) { return __builtin_amdgcn_rcpf(x); }

// One wave per 64x64 matrix; lane (bi,bj) owns an 8x8 sub-block held as f16:
//   bc[r][c2] = (E[r][2c2], E[r][2c2+1])   — packed along columns (row matvec)
//   br[c][r2] = (E[2r2][c], E[2r2+1][c])   — packed along row pairs (col matvec)
// Sinkhorn iterate M = E .* (u v^T). Key algebra: row update u' = u/(u*p+eps)
// with p = E.v reduces to u' = 1/p (eps=1e-9 is sub-ulp vs O(1) sums), so the
// per-iteration state is just the packed f16 vectors uuh, vvh.
__global__ __launch_bounds__(256, 5) void sinkhorn_kernel(
        const float* __restrict__ x, float* __restrict__ out, int nmat) {
    const int lane = threadIdx.x & 63;
    const int wave = threadIdx.x >> 6;
    const int mat  = blockIdx.x * 4 + wave;
    if (mat >= nmat) return;
    const int bi = lane >> 3;   // block-row 0..7
    const int bj = lane & 7;    // block-col 0..7

    const float4* __restrict__ xin = (const float4*)(x + (size_t)mat * 4096);

    half2_t bc[8][4];   // row-major, col-packed
    half2_t br[8][4];   // col-major, row-pair-packed
    #pragma unroll
    for (int r2 = 0; r2 < 4; ++r2) {
        float4 a0 = xin[(8 * bi + 2 * r2 + 0) * 16 + 2 * bj + 0];
        float4 a1 = xin[(8 * bi + 2 * r2 + 0) * 16 + 2 * bj + 1];
        float4 c0 = xin[(8 * bi + 2 * r2 + 1) * 16 + 2 * bj + 0];
        float4 c1 = xin[(8 * bi + 2 * r2 + 1) * 16 + 2 * bj + 1];
        float e0[8] = {__expf(a0.x), __expf(a0.y), __expf(a0.z), __expf(a0.w),
                       __expf(a1.x), __expf(a1.y), __expf(a1.z), __expf(a1.w)};
        float e1[8] = {__expf(c0.x), __expf(c0.y), __expf(c0.z), __expf(c0.w),
                       __expf(c1.x), __expf(c1.y), __expf(c1.z), __expf(c1.w)};
        #pragma unroll
        for (int c2 = 0; c2 < 4; ++c2) {
            bc[2 * r2 + 0][c2] = pkrtz(e0[2 * c2], e0[2 * c2 + 1]);
            bc[2 * r2 + 1][c2] = pkrtz(e1[2 * c2], e1[2 * c2 + 1]);
        }
        #pragma unroll
        for (int c = 0; c < 8; ++c)
            br[c][r2] = pkrtz(e0[c], e1[c]);
    }

    half2_t uuh[4], vvh[4];
    #pragma unroll
    for (int k = 0; k < 4; ++k) vvh[k] = pkrtz(1.0f, 1.0f);

    for (int it = 0; it < ITERS; ++it) {
        // ---- row phase: p_i = (E v)_i ; u' = 1/p ----
        float p[8];
        #pragma unroll
        for (int r = 0; r < 8; ++r) {
            float s = 0.0f;
            #pragma unroll
            for (int c2 = 0; c2 < 4; ++c2) s = fdot2(bc[r][c2], vvh[c2], s);
            p[r] = s;
        }
        #pragma unroll
        for (int r = 0; r < 8; ++r) p[r] = dpp_add<0xB1>(p[r]);   // xor1
        #pragma unroll
        for (int r = 0; r < 8; ++r) p[r] = dpp_add<0x4E>(p[r]);   // xor2
        #pragma unroll
        for (int r = 0; r < 8; ++r) p[r] = dpp_add<0x141>(p[r]);  // half-mirror completes 8
        #pragma unroll
        for (int k = 0; k < 4; ++k)
            uuh[k] = pkrtz(frcp(p[2 * k]), frcp(p[2 * k + 1]));

        // ---- col phase: q_j = (E^T u')_j ; v' = 1/q ----
        float q[8];
        #pragma unroll
        for (int c = 0; c < 8; ++c) {
            float s = 0.0f;
            #pragma unroll
            for (int r2 = 0; r2 < 4; ++r2) s = fdot2(br[c][r2], uuh[r2], s);
            q[c] = s;
        }
        #pragma unroll
        for (int c = 0; c < 8; ++c) q[c] = dpp_add<0x128>(q[c]);  // row_ror:8 = xor8
        #pragma unroll
        for (int c = 0; c < 8; ++c) q[c] = swap16_add(q[c]);      // xor16
        #pragma unroll
        for (int c = 0; c < 8; ++c) q[c] = swap32_add(q[c]);      // xor32
        #pragma unroll
        for (int k = 0; k < 4; ++k)
            vvh[k] = pkrtz(frcp(q[2 * k]), frcp(q[2 * k + 1]));
    }

    // ---- epilogue: out = E .* (u v^T), u/v unpacked from f16 ----
    float uf[8], vf[8];
    #pragma unroll
    for (int k = 0; k < 4; ++k) {
        uf[2 * k] = (float)uuh[k].x; uf[2 * k + 1] = (float)uuh[k].y;
        vf[2 * k] = (float)vvh[k].x; vf[2 * k + 1] = (float)vvh[k].y;
    }
    float4* __restrict__ o = (float4*)(out + (size_t)mat * 4096);
    #pragma unroll
    for (int r = 0; r < 8; ++r) {
        float ur = uf[r];
        float4 lo, hi;
        lo.x = (float)bc[r][0].x * ur * vf[0];
        lo.y = (float)bc[r][0].y * ur * vf[1];
        lo.z = (float)bc[r][1].x * ur * vf[2];
        lo.w = (float)bc[r][1].y * ur * vf[3];
        hi.x = (float)bc[r][2].x * ur * vf[4];
        hi.y = (float)bc[r][2].y * ur * vf[5];
        hi.z = (float)bc[r][3].x * ur * vf[6];
        hi.w = (float)bc[r][3].y * ur * vf[7];
        o[(8 * bi + r) * 16 + 2 * bj + 0] = lo;
        o[(8 * bi + r) * 16 + 2 * bj + 1] = hi;
    }
}

extern "C" void kernel_launch(void* const* d_in, const int* in_sizes, int n_in,
                              void* d_out, int out_size, void* d_ws, size_t ws_size,
                              hipStream_t stream) {
    const float* x = (const float*)d_in[0];
    float* out = (float*)d_out;
    const int nmat = in_sizes[0] / 4096;          // 8192 matrices of 64x64
    const int blocks = (nmat + 3) / 4;            // 4 matrices (waves) per block
    sinkhorn_kernel<<<blocks, 256, 0, stream>>>(x, out, nmat);
}